// Round 2
// baseline (129.620 us; speedup 1.0000x reference)
//
#include <hip/hip_runtime.h>
#include <math.h>

#define NUM_RBF 64
#define N_GRAPHS 64

// Stage 0a: fused table C = rbf_params * radial_filters  (T*T*64 floats, ws)
// Stage 0b: packed node records {x,y,z, type|batch<<8}    (N float4s, ws)
// Stage 1 : edge energy, 4 edges/thread via int4 edge loads, 2 float4 node
//           gathers/edge, 4 float4 fused-table loads for survivors,
//           LDS bins -> per-block partials in ws
// Stage 2 : reduce partials -> d_out (overwrites all 64 outputs; poison-safe)

__global__ __launch_bounds__(256) void build_table_kernel(
    const float4* __restrict__ p, const float4* __restrict__ f,
    float4* __restrict__ C, int n4)
{
    int i = blockIdx.x * blockDim.x + threadIdx.x;
    if (i < n4) {
        float4 a = p[i], b = f[i];
        C[i] = make_float4(a.x * b.x, a.y * b.y, a.z * b.z, a.w * b.w);
    }
}

__global__ __launch_bounds__(256) void pack_nodes_kernel(
    const float* __restrict__ pos, const int* __restrict__ types,
    const int* __restrict__ batch, float4* __restrict__ rec, int N)
{
    int i = blockIdx.x * blockDim.x + threadIdx.x;
    if (i < N) {
        int bits = (types[i] & 0xFF) | ((batch[i] & 0xFF) << 8);
        rec[i] = make_float4(pos[3 * i], pos[3 * i + 1], pos[3 * i + 2],
                             __int_as_float(bits));
    }
}

__global__ __launch_bounds__(256) void edge_energy_kernel(
    const int*    __restrict__ edge_index,
    const float4* __restrict__ rec,
    const float4* __restrict__ C4,     // fused table as float4
    float*        __restrict__ partial,
    int E, int T)
{
    __shared__ float bins[N_GRAPHS];
    for (int i = threadIdx.x; i < N_GRAPHS; i += blockDim.x) bins[i] = 0.0f;
    __syncthreads();

    const float CUTOFF      = 5.0f;
    const float gamma       = (NUM_RBF / CUTOFF) * (NUM_RBF / CUTOFF);   // 163.84
    const float spacing     = CUTOFF / (float)(NUM_RBF - 1);             // 5/63
    const float inv_spacing = (float)(NUM_RBF - 1) / CUTOFF;
    const float pi_over_c   = (float)M_PI / CUTOFF;

    const int nq     = (E + 3) >> 2;                 // quads of edges
    const int stride = gridDim.x * blockDim.x;

    for (int q = blockIdx.x * blockDim.x + threadIdx.x; q < nq; q += stride) {
        const int e0 = q << 2;

        int s[4], t[4];
        int cnt;
        if (e0 + 3 < E) {
            const int4 sv = *(const int4*)(edge_index + e0);
            const int4 tv = *(const int4*)(edge_index + E + e0);
            s[0] = sv.x; s[1] = sv.y; s[2] = sv.z; s[3] = sv.w;
            t[0] = tv.x; t[1] = tv.y; t[2] = tv.z; t[3] = tv.w;
            cnt = 4;
        } else {
            cnt = E - e0;
            for (int k = 0; k < cnt; ++k) {
                s[k] = edge_index[e0 + k];
                t[k] = edge_index[E + e0 + k];
            }
        }

        // issue all node gathers up front (ILP for latency hiding)
        float4 rs[4], rd[4];
        for (int k = 0; k < cnt; ++k) { rs[k] = rec[s[k]]; rd[k] = rec[t[k]]; }

        for (int k = 0; k < cnt; ++k) {
            const float dx = rd[k].x - rs[k].x;
            const float dy = rd[k].y - rs[k].y;
            const float dz = rd[k].z - rs[k].z;
            const float d  = sqrtf(dx * dx + dy * dy + dz * dz + 1e-12f);

            if (d < CUTOFF) {
                const int sb = __float_as_int(rs[k].w);
                const int db = __float_as_int(rd[k].w);
                const int ts = sb & 0xFF;
                const int td = db & 0xFF;
                const int lo = min(ts, td);
                const int hi = max(ts, td);
                const int base = (lo * T + hi) * NUM_RBF;

                // 16-tap window, start aligned down to x4; covers >= +-5.5
                // spacings around d (dropped terms < 6e-12)
                const float c = d * inv_spacing;
                int a0 = (int)floorf(c - 5.5f);
                a0 &= ~3;
                a0 = max(0, min(NUM_RBF - 16, a0));

                const float4* w = C4 + ((base + a0) >> 2);
                float acc = 0.0f;
                float delta = d - (float)a0 * spacing;
#pragma unroll
                for (int j = 0; j < 4; ++j) {
                    const float4 cv = w[j];
                    float d0 = delta;
                    float d1 = delta - spacing;
                    float d2 = delta - 2.0f * spacing;
                    float d3 = delta - 3.0f * spacing;
                    acc += cv.x * __expf(-gamma * d0 * d0);
                    acc += cv.y * __expf(-gamma * d1 * d1);
                    acc += cv.z * __expf(-gamma * d2 * d2);
                    acc += cv.w * __expf(-gamma * d3 * d3);
                    delta -= 4.0f * spacing;
                }
                const float fc = 0.5f * (__cosf(pi_over_c * d) + 1.0f);
                atomicAdd(&bins[(sb >> 8) & 0xFF], acc * fc);
            }
        }
    }

    __syncthreads();
    for (int i = threadIdx.x; i < N_GRAPHS; i += blockDim.x)
        partial[blockIdx.x * N_GRAPHS + i] = bins[i];
}

__global__ __launch_bounds__(256) void reduce_kernel(
    const float* __restrict__ partial, float* __restrict__ out, int nblocks)
{
    const int g = blockIdx.x;
    float s = 0.0f;
    for (int i = threadIdx.x; i < nblocks; i += blockDim.x)
        s += partial[i * N_GRAPHS + g];

    for (int off = 32; off > 0; off >>= 1)
        s += __shfl_down(s, off, 64);

    __shared__ float red[4];
    const int wave = threadIdx.x >> 6;
    const int lane = threadIdx.x & 63;
    if (lane == 0) red[wave] = s;
    __syncthreads();
    if (threadIdx.x == 0)
        out[g] = red[0] + red[1] + red[2] + red[3];
}

extern "C" void kernel_launch(void* const* d_in, const int* in_sizes, int n_in,
                              void* d_out, int out_size, void* d_ws, size_t ws_size,
                              hipStream_t stream) {
    const float* pos            = (const float*)d_in[0];
    const float* rbf_params     = (const float*)d_in[1];
    const float* radial_filters = (const float*)d_in[2];
    const int*   edge_index     = (const int*)d_in[3];
    const int*   atom_types     = (const int*)d_in[4];
    const int*   batch          = (const int*)d_in[5];
    float*       out            = (float*)d_out;

    const int E = in_sizes[3] / 2;
    const int N = in_sizes[4];
    int T = 1;
    while ((T + 1) * (T + 1) * NUM_RBF <= in_sizes[1]) ++T;
    const int tbl_elems = T * T * NUM_RBF;          // multiple of 4

    // workspace layout (floats): [table | node recs | partials]
    float*  Ctab    = (float*)d_ws;
    float4* recs    = (float4*)((char*)d_ws + ((size_t)tbl_elems * 4 + 255) / 256 * 256);
    float*  partial = (float*)((char*)recs + (size_t)N * 16);

    const int nq = (E + 3) >> 2;
    int nblocks = (nq + 255) / 256;                 // one quad per thread
    // cap by workspace (partials need nblocks*64 floats)
    const size_t part_off = (size_t)((char*)partial - (char*)d_ws);
    const size_t avail = (ws_size > part_off) ? (ws_size - part_off) : 0;
    const int maxb = (int)(avail / (N_GRAPHS * sizeof(float)));
    if (nblocks > maxb) nblocks = maxb > 0 ? maxb : 1;

    build_table_kernel<<<(tbl_elems / 4 + 255) / 256, 256, 0, stream>>>(
        (const float4*)rbf_params, (const float4*)radial_filters,
        (float4*)Ctab, tbl_elems / 4);
    pack_nodes_kernel<<<(N + 255) / 256, 256, 0, stream>>>(
        pos, atom_types, batch, recs, N);
    edge_energy_kernel<<<nblocks, 256, 0, stream>>>(
        edge_index, recs, (const float4*)Ctab, partial, E, T);
    reduce_kernel<<<N_GRAPHS, 256, 0, stream>>>(partial, out, nblocks);
}

// Round 3
// 97.565 us; speedup vs baseline: 1.3285x; 1.3285x over previous
//
#include <hip/hip_runtime.h>
#include <math.h>

#define NUM_RBF 64
#define N_GRAPHS 64

// Stage 0a: fused table C = rbf_params * radial_filters  (T*T*64 floats, ws)
// Stage 0b: packed node records {x,y,z, type|batch<<8}    (N float4s, ws)
// Stage 1 : edge energy, 4 edges/thread FULLY UNROLLED (no runtime-indexed
//           arrays -> no scratch spill), 2 float4 node gathers/edge,
//           3 float4 fused-table loads for survivors (12-tap window),
//           LDS bins -> per-block partials in ws
// Stage 2 : reduce partials -> d_out (overwrites all 64 outputs; poison-safe)

__global__ __launch_bounds__(256) void build_table_kernel(
    const float4* __restrict__ p, const float4* __restrict__ f,
    float4* __restrict__ C, int n4)
{
    int i = blockIdx.x * blockDim.x + threadIdx.x;
    if (i < n4) {
        float4 a = p[i], b = f[i];
        C[i] = make_float4(a.x * b.x, a.y * b.y, a.z * b.z, a.w * b.w);
    }
}

__global__ __launch_bounds__(256) void pack_nodes_kernel(
    const float* __restrict__ pos, const int* __restrict__ types,
    const int* __restrict__ batch, float4* __restrict__ rec, int N)
{
    int i = blockIdx.x * blockDim.x + threadIdx.x;
    if (i < N) {
        int bits = (types[i] & 0xFF) | ((batch[i] & 0xFF) << 8);
        rec[i] = make_float4(pos[3 * i], pos[3 * i + 1], pos[3 * i + 2],
                             __int_as_float(bits));
    }
}

#define CUTOFF_F      5.0f
#define GAMMA_F       163.84f                    /* (64/5)^2            */
#define SPACING_F     (5.0f / 63.0f)
#define INV_SPACING_F (63.0f / 5.0f)
#define PI_OVER_C_F   (3.14159265358979f / 5.0f)

__device__ __forceinline__ void edge_body(
    float4 rs, float4 rd, const float4* __restrict__ C4, int T,
    float* __restrict__ bins)
{
    const float dx = rd.x - rs.x;
    const float dy = rd.y - rs.y;
    const float dz = rd.z - rs.z;
    const float d  = sqrtf(dx * dx + dy * dy + dz * dz + 1e-12f);
    if (d >= CUTOFF_F) return;

    const int sb = __float_as_int(rs.w);
    const int db = __float_as_int(rd.w);
    const int ts = sb & 0xFF;
    const int td = db & 0xFF;
    const int lo = min(ts, td);
    const int hi = max(ts, td);
    const int base = (lo * T + hi) * NUM_RBF;

    // 12-tap window, start aligned to x4; covers >= +-3.5 spacings
    // (dropped terms < 3.2e-6 * |coef|; threshold ~1.0)
    const float c = d * INV_SPACING_F;
    int a0 = ((int)floorf(c - 3.5f)) & ~3;
    a0 = max(0, min(NUM_RBF - 12, a0));

    const float4* w = C4 + ((base + a0) >> 2);
    float acc = 0.0f;
    float delta = d - (float)a0 * SPACING_F;
#pragma unroll
    for (int j = 0; j < 3; ++j) {
        const float4 cv = w[j];
        const float d0 = delta;
        const float d1 = delta - SPACING_F;
        const float d2 = delta - 2.0f * SPACING_F;
        const float d3 = delta - 3.0f * SPACING_F;
        acc += cv.x * __expf(-GAMMA_F * d0 * d0);
        acc += cv.y * __expf(-GAMMA_F * d1 * d1);
        acc += cv.z * __expf(-GAMMA_F * d2 * d2);
        acc += cv.w * __expf(-GAMMA_F * d3 * d3);
        delta -= 4.0f * SPACING_F;
    }
    const float fc = 0.5f * (__cosf(PI_OVER_C_F * d) + 1.0f);
    atomicAdd(&bins[(sb >> 8) & 0xFF], acc * fc);
}

__global__ __launch_bounds__(256) void edge_energy_kernel(
    const int*    __restrict__ edge_index,
    const float4* __restrict__ rec,
    const float4* __restrict__ C4,
    float*        __restrict__ partial,
    int E, int T)
{
    __shared__ float bins[N_GRAPHS];
    for (int i = threadIdx.x; i < N_GRAPHS; i += blockDim.x) bins[i] = 0.0f;
    __syncthreads();

    const int nfull  = E >> 2;                      // full quads only
    const int stride = gridDim.x * blockDim.x;
    const int gid    = blockIdx.x * blockDim.x + threadIdx.x;

    for (int q = gid; q < nfull; q += stride) {
        const int e0 = q << 2;
        const int4 sv = *(const int4*)(edge_index + e0);
        const int4 tv = *(const int4*)(edge_index + E + e0);

        // 8 independent gathers in flight (all compile-time register slots)
        const float4 rs0 = rec[sv.x], rd0 = rec[tv.x];
        const float4 rs1 = rec[sv.y], rd1 = rec[tv.y];
        const float4 rs2 = rec[sv.z], rd2 = rec[tv.z];
        const float4 rs3 = rec[sv.w], rd3 = rec[tv.w];

        edge_body(rs0, rd0, C4, T, bins);
        edge_body(rs1, rd1, C4, T, bins);
        edge_body(rs2, rd2, C4, T, bins);
        edge_body(rs3, rd3, C4, T, bins);
    }

    // tail edges (E % 4): one thread, direct loads
    if (gid == 0) {
        for (int e = nfull << 2; e < E; ++e) {
            const float4 rs = rec[edge_index[e]];
            const float4 rd = rec[edge_index[E + e]];
            edge_body(rs, rd, C4, T, bins);
        }
    }

    __syncthreads();
    for (int i = threadIdx.x; i < N_GRAPHS; i += blockDim.x)
        partial[blockIdx.x * N_GRAPHS + i] = bins[i];
}

__global__ __launch_bounds__(256) void reduce_kernel(
    const float* __restrict__ partial, float* __restrict__ out, int nblocks)
{
    const int g = blockIdx.x;
    float s = 0.0f;
    for (int i = threadIdx.x; i < nblocks; i += blockDim.x)
        s += partial[i * N_GRAPHS + g];

    for (int off = 32; off > 0; off >>= 1)
        s += __shfl_down(s, off, 64);

    __shared__ float red[4];
    const int wave = threadIdx.x >> 6;
    const int lane = threadIdx.x & 63;
    if (lane == 0) red[wave] = s;
    __syncthreads();
    if (threadIdx.x == 0)
        out[g] = red[0] + red[1] + red[2] + red[3];
}

extern "C" void kernel_launch(void* const* d_in, const int* in_sizes, int n_in,
                              void* d_out, int out_size, void* d_ws, size_t ws_size,
                              hipStream_t stream) {
    const float* pos            = (const float*)d_in[0];
    const float* rbf_params     = (const float*)d_in[1];
    const float* radial_filters = (const float*)d_in[2];
    const int*   edge_index     = (const int*)d_in[3];
    const int*   atom_types     = (const int*)d_in[4];
    const int*   batch          = (const int*)d_in[5];
    float*       out            = (float*)d_out;

    const int E = in_sizes[3] / 2;
    const int N = in_sizes[4];
    int T = 1;
    while ((T + 1) * (T + 1) * NUM_RBF <= in_sizes[1]) ++T;
    const int tbl_elems = T * T * NUM_RBF;          // multiple of 4

    // workspace layout (256B aligned): [table | node recs | partials]
    float*  Ctab    = (float*)d_ws;
    float4* recs    = (float4*)((char*)d_ws + ((size_t)tbl_elems * 4 + 255) / 256 * 256);
    float*  partial = (float*)((char*)recs + (size_t)N * 16);

    const int nq = E >> 2;
    int nblocks = (nq + 255) / 256;                 // one quad per thread
    const size_t part_off = (size_t)((char*)partial - (char*)d_ws);
    const size_t avail = (ws_size > part_off) ? (ws_size - part_off) : 0;
    const int maxb = (int)(avail / (N_GRAPHS * sizeof(float)));
    if (nblocks > maxb) nblocks = maxb > 0 ? maxb : 1;
    if (nblocks < 1) nblocks = 1;

    build_table_kernel<<<(tbl_elems / 4 + 255) / 256, 256, 0, stream>>>(
        (const float4*)rbf_params, (const float4*)radial_filters,
        (float4*)Ctab, tbl_elems / 4);
    pack_nodes_kernel<<<(N + 255) / 256, 256, 0, stream>>>(
        pos, atom_types, batch, recs, N);
    edge_energy_kernel<<<nblocks, 256, 0, stream>>>(
        edge_index, recs, (const float4*)Ctab, partial, E, T);
    reduce_kernel<<<N_GRAPHS, 256, 0, stream>>>(partial, out, nblocks);
}

// Round 5
// 94.915 us; speedup vs baseline: 1.3657x; 1.0279x over previous
//
#include <hip/hip_runtime.h>
#include <math.h>

#define NUM_RBF 64
#define N_GRAPHS 64

typedef int   int4v   __attribute__((ext_vector_type(4)));
typedef float float4v __attribute__((ext_vector_type(4)));

// Stage 0 : fused table C = rbf_params * radial_filters  AND packed node
//           records {x,y,z, type|batch<<8} in one launch.
// Stage 1 : edge energy. 4 edges/thread, int4 nontemporal edge loads,
//           2 float4 node gathers/edge, 12-tap Gaussian window via a
//           multiplicative recurrence (3 exps + 1 cos per edge),
//           LDS bins -> per-block partials in ws.
// Stage 2 : reduce partials -> d_out (writes all 64 outputs; poison-safe).

__global__ __launch_bounds__(256) void prologue_kernel(
    const float4v* __restrict__ p, const float4v* __restrict__ f,
    float4v* __restrict__ C, int n4,
    const float* __restrict__ pos, const int* __restrict__ types,
    const int* __restrict__ batch, float4v* __restrict__ rec, int N)
{
    int i = blockIdx.x * blockDim.x + threadIdx.x;
    if (i < n4) C[i] = p[i] * f[i];
    if (i < N) {
        int bits = (types[i] & 0xFF) | ((batch[i] & 0xFF) << 8);
        float4v r = { pos[3 * i], pos[3 * i + 1], pos[3 * i + 2],
                      __int_as_float(bits) };
        rec[i] = r;
    }
}

#define CUTOFF_F      5.0f
#define GAMMA_F       163.84f                    /* (64/5)^2                  */
#define SPACING_F     (float)(5.0 / 63.0)
#define INV_SPACING_F (float)(63.0 / 5.0)
#define PI_OVER_C_F   (float)(3.14159265358979323846 / 5.0)
#define TWO_GAMMA_S_F (float)(2.0 * 163.84 * 5.0 / 63.0)   /* 26.00635 */
// v = exp(-gamma*s^2) = exp(-(64/63)^2)
#define LN_V          (-(64.0 / 63.0) * (64.0 / 63.0))
#define V_1           (float)exp(LN_V)           /* v    (first ratio factor) */
#define V_2           (float)exp(2.0 * LN_V)     /* v^2  (per-step multiplier)*/

__device__ __forceinline__ void edge_body(
    float4v rs, float4v rd, const float4v* __restrict__ C4, int T,
    float* __restrict__ bins)
{
    const float dx = rd.x - rs.x;
    const float dy = rd.y - rs.y;
    const float dz = rd.z - rs.z;
    const float d  = sqrtf(dx * dx + dy * dy + dz * dz + 1e-12f);
    if (d >= CUTOFF_F) return;

    const int sb = __float_as_int(rs.w);
    const int db = __float_as_int(rd.w);
    const int ts = sb & 0xFF;
    const int td = db & 0xFF;
    const int lo = min(ts, td);
    const int hi = max(ts, td);
    const int base = (lo * T + hi) * NUM_RBF;

    // 12-tap window, start aligned to x4; covers >= +-3.5 spacings
    const float c = d * INV_SPACING_F;
    int a0 = ((int)floorf(c - 3.5f)) & ~3;
    a0 = max(0, min(NUM_RBF - 12, a0));

    const float4v* w = C4 + ((base + a0) >> 2);
    const float4v w0 = w[0], w1 = w[1], w2 = w[2];

    // Taps t_k = exp(-gamma*(delta-k*s)^2), k=0..11, anchored at k=5:
    //   up  : t_{k+1} = t_k * m,  m0 = u  * v,  m *= v^2 per step
    //   down: t_{k-1} = t_k * m,  m0 = ui * v,  m *= v^2 per step
    //   u = exp(+2*gamma*s*d5), ui = 1/u, d5 = delta - 5s, v = exp(-gamma*s^2)
    // (verified vs direct exp at delta=0.4: t4/t6/t7 match to 5 digits;
    //  max intermediate u = e^12.4 — no overflow in the clamp corners)
    const float delta = d - (float)a0 * SPACING_F;
    const float d5 = delta - 5.0f * SPACING_F;
    const float t5 = __expf(-GAMMA_F * d5 * d5);
    const float x  = TWO_GAMMA_S_F * d5;
    const float u  = __expf(x);
    const float ui = __expf(-x);

    float acc = w1.y * t5;                 // k=5
    float t = t5, m = u * V_1;             // upward k=6..11
    t *= m;  acc += w1.z * t;  m *= V_2;
    t *= m;  acc += w1.w * t;  m *= V_2;
    t *= m;  acc += w2.x * t;  m *= V_2;
    t *= m;  acc += w2.y * t;  m *= V_2;
    t *= m;  acc += w2.z * t;  m *= V_2;
    t *= m;  acc += w2.w * t;
    t = t5;  m = ui * V_1;                 // downward k=4..0
    t *= m;  acc += w1.x * t;  m *= V_2;
    t *= m;  acc += w0.w * t;  m *= V_2;
    t *= m;  acc += w0.z * t;  m *= V_2;
    t *= m;  acc += w0.y * t;  m *= V_2;
    t *= m;  acc += w0.x * t;

    const float fc = 0.5f * (__cosf(PI_OVER_C_F * d) + 1.0f);
    atomicAdd(&bins[(sb >> 8) & 0xFF], acc * fc);
}

__global__ __launch_bounds__(256) void edge_energy_kernel(
    const int*     __restrict__ edge_index,
    const float4v* __restrict__ rec,
    const float4v* __restrict__ C4,
    float*         __restrict__ partial,
    int E, int T)
{
    __shared__ float bins[N_GRAPHS];
    for (int i = threadIdx.x; i < N_GRAPHS; i += blockDim.x) bins[i] = 0.0f;
    __syncthreads();

    const int nfull  = E >> 2;
    const int stride = gridDim.x * blockDim.x;
    const int gid    = blockIdx.x * blockDim.x + threadIdx.x;

    for (int q = gid; q < nfull; q += stride) {
        const int e0 = q << 2;
        // nontemporal: 12.8 MB once-streamed index data must not evict the
        // hot node-record / table working set from L2
        const int4v sv = __builtin_nontemporal_load(
            (const int4v*)(edge_index + e0));
        const int4v tv = __builtin_nontemporal_load(
            (const int4v*)(edge_index + E + e0));

        const float4v rs0 = rec[sv.x], rd0 = rec[tv.x];
        const float4v rs1 = rec[sv.y], rd1 = rec[tv.y];
        const float4v rs2 = rec[sv.z], rd2 = rec[tv.z];
        const float4v rs3 = rec[sv.w], rd3 = rec[tv.w];

        edge_body(rs0, rd0, C4, T, bins);
        edge_body(rs1, rd1, C4, T, bins);
        edge_body(rs2, rd2, C4, T, bins);
        edge_body(rs3, rd3, C4, T, bins);
    }

    if (gid == 0) {                       // tail edges (E % 4)
        for (int e = nfull << 2; e < E; ++e) {
            const float4v rs = rec[edge_index[e]];
            const float4v rd = rec[edge_index[E + e]];
            edge_body(rs, rd, C4, T, bins);
        }
    }

    __syncthreads();
    for (int i = threadIdx.x; i < N_GRAPHS; i += blockDim.x)
        partial[blockIdx.x * N_GRAPHS + i] = bins[i];
}

__global__ __launch_bounds__(256) void reduce_kernel(
    const float* __restrict__ partial, float* __restrict__ out, int nblocks)
{
    const int g = blockIdx.x;
    float s = 0.0f;
    for (int i = threadIdx.x; i < nblocks; i += blockDim.x)
        s += partial[i * N_GRAPHS + g];

    for (int off = 32; off > 0; off >>= 1)
        s += __shfl_down(s, off, 64);

    __shared__ float red[4];
    const int wave = threadIdx.x >> 6;
    const int lane = threadIdx.x & 63;
    if (lane == 0) red[wave] = s;
    __syncthreads();
    if (threadIdx.x == 0)
        out[g] = red[0] + red[1] + red[2] + red[3];
}

extern "C" void kernel_launch(void* const* d_in, const int* in_sizes, int n_in,
                              void* d_out, int out_size, void* d_ws, size_t ws_size,
                              hipStream_t stream) {
    const float* pos            = (const float*)d_in[0];
    const float* rbf_params     = (const float*)d_in[1];
    const float* radial_filters = (const float*)d_in[2];
    const int*   edge_index     = (const int*)d_in[3];
    const int*   atom_types     = (const int*)d_in[4];
    const int*   batch          = (const int*)d_in[5];
    float*       out            = (float*)d_out;

    const int E = in_sizes[3] / 2;
    const int N = in_sizes[4];
    int T = 1;
    while ((T + 1) * (T + 1) * NUM_RBF <= in_sizes[1]) ++T;
    const int tbl_elems = T * T * NUM_RBF;          // multiple of 4

    // workspace layout (256B aligned): [table | node recs | partials]
    float*   Ctab    = (float*)d_ws;
    float4v* recs    = (float4v*)((char*)d_ws + ((size_t)tbl_elems * 4 + 255) / 256 * 256);
    float*   partial = (float*)((char*)recs + (size_t)N * 16);

    const int nq = E >> 2;
    int nblocks = (nq + 255) / 256;                 // one quad per thread
    const size_t part_off = (size_t)((char*)partial - (char*)d_ws);
    const size_t avail = (ws_size > part_off) ? (ws_size - part_off) : 0;
    const int maxb = (int)(avail / (N_GRAPHS * sizeof(float)));
    if (nblocks > maxb) nblocks = maxb > 0 ? maxb : 1;
    if (nblocks < 1) nblocks = 1;

    const int pro_n = max(tbl_elems / 4, N);
    prologue_kernel<<<(pro_n + 255) / 256, 256, 0, stream>>>(
        (const float4v*)rbf_params, (const float4v*)radial_filters,
        (float4v*)Ctab, tbl_elems / 4, pos, atom_types, batch, recs, N);
    edge_energy_kernel<<<nblocks, 256, 0, stream>>>(
        edge_index, recs, (const float4v*)Ctab, partial, E, T);
    reduce_kernel<<<N_GRAPHS, 256, 0, stream>>>(partial, out, nblocks);
}